// Round 4
// baseline (12465.202 us; speedup 1.0000x reference)
//
#include <hip/hip_runtime.h>
#include <cstdint>
#include <cstddef>

typedef __bf16 bf16x8 __attribute__((ext_vector_type(8)));
typedef __bf16 bf16x4 __attribute__((ext_vector_type(4)));
typedef float  f32x4  __attribute__((ext_vector_type(4)));

// ---------------- ws layout (bytes) ----------------
#define WS_WFRAG   0            // 12,582,912 : fused W bf16 fragments
#define WS_XB      12582912     // 16,777,216 : x in bf16
#define WS_XCHG    29360128     // 33,554,432 : 512 slots * 64 KiB (fresh h exchange)
#define WS_CNT     62914560     // 16,384     : 2 groups * 64 lines * 128 B
#define WS_NEEDED  62930944

// LDS layout (bytes): X wave-private dbuf @0 (65536 = 2w*2buf*16K) |
//                     W @65536 (32768) | scr @98304 (2176)
#define LDS_BYTES  100480

#define SENT 0xFFFFFFFFFFFFFFFFULL

__device__ __forceinline__ void gload16(const void* g, void* l) {
    __builtin_amdgcn_global_load_lds(
        (const __attribute__((address_space(1))) void*)(g),
        (__attribute__((address_space(3))) void*)(l),
        16, 0, 0);
}

__device__ __forceinline__ float sigmoidf_(float x) {
    return 1.f / (1.f + __expf(-x));
}
__device__ __forceinline__ float tanhf_(float x) {
    x = fminf(fmaxf(x, -15.f), 15.f);
    float e2 = __expf(2.f * x);
    return (e2 - 1.f) / (e2 + 1.f);
}

__device__ __forceinline__ bf16x8 mkfrag(unsigned long long lo, unsigned long long hi) {
    union { unsigned long long u[2]; bf16x8 v; } x;
    x.u[0] = lo; x.u[1] = hi;
    return x.v;
}

// ---- prep: shuffle fused W = [Wx ; Wh] into bf16 B-fragment order ----
__global__ void __launch_bounds__(256) prep_w_kernel(const float* __restrict__ Wx,
                                                     const float* __restrict__ Wh,
                                                     __bf16* __restrict__ wfrag) {
    int tid = blockIdx.x * 256 + threadIdx.x;   // 0 .. 786431
    int l   = tid & 63;
    int m   = tid >> 6;
    int nt  = m & 1;
    int sk  = m >> 1;
    int kk  = sk % 48;
    int s   = sk / 48;
    int lc  = l & 15;
    int c   = nt * 16 + lc;
    int uu  = c >> 2;
    int gi  = c & 3;
    int n   = gi * 1024 + s * 8 + uu;
    int k0  = kk * 32 + (l >> 4) * 8;
    bf16x8 v;
#pragma unroll
    for (int j = 0; j < 8; ++j) {
        int k  = k0 + j;
        float f = (k < 512) ? Wx[k * 4096 + n] : Wh[(k - 512) * 4096 + n];
        v[j] = (__bf16)f;
    }
    ((bf16x8*)wfrag)[tid] = v;
}

// ---- prep: cast data fp32 -> bf16 ----
__global__ void __launch_bounds__(256) prep_x_kernel(const float* __restrict__ data,
                                                     __bf16* __restrict__ xb) {
    int tid = blockIdx.x * 256 + threadIdx.x;
    float4 v = ((const float4*)data)[tid];
    bf16x4 o;
    o[0] = (__bf16)v.x; o[1] = (__bf16)v.y; o[2] = (__bf16)v.z; o[3] = (__bf16)v.w;
    ((bf16x4*)xb)[tid] = o;
}

// ---- persistent LSTM kernel ----
// grid = 256 blocks x 128 threads. block -> (g = bid>>7, s = bid&127).
// ZERO in-loop barriers; waves fully independent (X wave-private, scr
// wave-local, W read-only). Sync = pacing counter + sentinel backstop:
//  * producers: pack -> agent store (fire-forget) -> lane0 counter add
//    (fire-forget, 64-line spread: 4 adds/line). No vmcnt ack.
//  * consumers: wave-uniform poll of the 64 counter lines to target
//    256*(t+1)-SLACK, then plain cached loads of h (fresh address / step).
//    Any 8B half still sentinel (0xFF... impossible for packed bf16 h) is
//    re-read with agent-scope atomic loads (L3-fresh) + s_sleep backoff.
//    Rare by construction; deadlock-free (every wave adds BEFORE polling).
//  * the poll's result consumption forces vmcnt drain -> previous x-prefetch
//    DMA (global_load_lds) is complete before the next iteration reads X_lds.
__global__ void __launch_bounds__(128, 1)
lstm_main(const __bf16* __restrict__ xb, const __bf16* __restrict__ wfrag,
          const float* __restrict__ bias, float* __restrict__ out,
          __bf16* __restrict__ hbuf, unsigned* __restrict__ cnt) {
    extern __shared__ char smem[];
    __bf16* W_lds = (__bf16*)(smem + 65536);       // 32 chunks (kk 0..15 x {nt0,nt1})
    float*  scr   = (float*)(smem + 98304);        // 2 * 272 floats (wave-local)

    const int tid = threadIdx.x;
    const int l   = tid & 63;
    const int w   = tid >> 6;        // wave id == N-tile id (0,1)
    const int q   = l >> 4;
    const int r   = l & 15;
    const int bid = blockIdx.x;
    const int s   = bid & 127;
    const int g   = bid >> 7;
    const int gb0 = g * 16;

    __bf16* Xw = (__bf16*)(smem + w * 32768);      // wave-private: 2 bufs * 8192 elems

    const __bf16* wsrc = wfrag + (size_t)s * 49152;
    // ---- stage Wx part (chunks 0..31) into LDS ----
    for (int m = w * 16; m < w * 16 + 16; ++m) {
        gload16(wsrc + m * 512 + l * 8, W_lds + m * 512);
    }
    // ---- Wh part in registers: chunk ((16+j)*2 + w), j = kk-16 ----
    bf16x8 wreg[32];
#pragma unroll
    for (int j = 0; j < 32; ++j)
        wreg[j] = *(const bf16x8*)(wsrc + (size_t)((16 + j) * 2 + w) * 512 + l * 8);

    const int uu = w * 4 + q;
    const int u  = s * 8 + uu;
    const float b_i = bias[u];
    const float b_f = bias[1024 + u];
    const float b_g = bias[2048 + u];
    const float b_o = bias[3072 + u];
    float cst = 0.f;

    unsigned* cbase = cnt + g * 2048;                       // 64 lines * 128 B
    unsigned* mycnt = cbase + ((s * 2 + w) & 63) * 32;      // 4 waves per line

    // ---- prefetch x_0 into X buffer 0 (wave-private, all 16 chunks) ----
    const __bf16* xrow = xb + (size_t)(gb0 + r) * 512 * 512;
#pragma unroll
    for (int m = 0; m < 16; ++m) {
        gload16(xrow + m * 32 + q * 8, Xw + m * 512);
    }

    // ---- issue h_0 loads (slot 0 zero-filled; plain loads, no sentinel) ----
    const char* xch = (const char*)hbuf;
    ulonglong2 hv[32];
    {
        const char* hsrc = xch + (size_t)g * 32768;
#pragma unroll
        for (int j = 0; j < 32; ++j)
            hv[j] = *(const ulonglong2*)(hsrc + (j * 4 + q) * 256 + r * 16);
    }

    __syncthreads();   // init only: drains W + x_0 DMA

    for (int t = 0; t < 512; ++t) {
        // ---- x-part MFMAs (A from wave-private X_lds, B from W_lds) ----
        const __bf16* Xc = Xw + (t & 1) * 8192;
        f32x4 acc0 = {0.f, 0.f, 0.f, 0.f};
        f32x4 acc1 = {0.f, 0.f, 0.f, 0.f};
#pragma unroll
        for (int kk = 0; kk < 16; kk += 2) {
            acc0 = __builtin_amdgcn_mfma_f32_16x16x32_bf16(
                *(const bf16x8*)(Xc + kk * 512 + l * 8),
                *(const bf16x8*)(W_lds + (kk * 2 + w) * 512 + l * 8), acc0, 0, 0, 0);
            acc1 = __builtin_amdgcn_mfma_f32_16x16x32_bf16(
                *(const bf16x8*)(Xc + (kk + 1) * 512 + l * 8),
                *(const bf16x8*)(W_lds + ((kk + 1) * 2 + w) * 512 + l * 8), acc1, 0, 0, 0);
        }

        // ---- sentinel validation of h_t (rare atomic retry for stragglers) ----
        {
            const char* hsrc = xch + (size_t)t * 65536 + (size_t)g * 32768;
            for (;;) {
                int miss = 0;
#pragma unroll
                for (int j = 0; j < 32; ++j)
                    miss += (hv[j].x == SENT) + (hv[j].y == SENT);
                if (miss == 0) break;
                __builtin_amdgcn_s_sleep(1);
#pragma unroll
                for (int j = 0; j < 32; ++j) {
                    const unsigned long long* p =
                        (const unsigned long long*)(hsrc + (j * 4 + q) * 256 + r * 16);
                    if (hv[j].x == SENT)
                        hv[j].x = __hip_atomic_load(p,     __ATOMIC_RELAXED, __HIP_MEMORY_SCOPE_AGENT);
                    if (hv[j].y == SENT)
                        hv[j].y = __hip_atomic_load(p + 1, __ATOMIC_RELAXED, __HIP_MEMORY_SCOPE_AGENT);
                }
            }
        }

        // ---- h-part MFMAs, kk ascending, acc0=even / acc1=odd (order preserved) ----
#pragma unroll
        for (int j = 0; j < 32; j += 2) {
            acc0 = __builtin_amdgcn_mfma_f32_16x16x32_bf16(
                mkfrag(hv[j].x, hv[j].y),         wreg[j],     acc0, 0, 0, 0);
            acc1 = __builtin_amdgcn_mfma_f32_16x16x32_bf16(
                mkfrag(hv[j + 1].x, hv[j + 1].y), wreg[j + 1], acc1, 0, 0, 0);
        }

        // ---- regroup gates via wave-local scratch ----
        float* sw = scr + w * 272;
#pragma unroll
        for (int rg = 0; rg < 4; ++rg) {
            sw[(l & 15) * 17 + q * 4 + rg] = acc0[rg] + acc1[rg];
        }
        float xi = sw[(q * 4 + 0) * 17 + r];
        float xf = sw[(q * 4 + 1) * 17 + r];
        float xg = sw[(q * 4 + 2) * 17 + r];
        float xo = sw[(q * 4 + 3) * 17 + r];

        float ii = sigmoidf_(xi + b_i);
        float ff = sigmoidf_(xf + b_f);
        float gg = tanhf_(xg + b_g);
        float oo = sigmoidf_(xo + b_o);
        cst = ff * cst + ii * gg;
        float h = oo * tanhf_(cst);

        if (t < 511) {
            // ---- pack h via shuffles; q-lanes 0..15 of EACH wave store 8B ----
            float h1 = __shfl_xor(h, 16);
            float h2 = __shfl_xor(h, 32);
            float h3 = __shfl_xor(h, 48);
            if ((l & 48) == 0) {
                union { bf16x4 v; unsigned long long uv; } pk;
                pk.v[0] = (__bf16)h;  pk.v[1] = (__bf16)h1;
                pk.v[2] = (__bf16)h2; pk.v[3] = (__bf16)h3;
                unsigned long long* dst = (unsigned long long*)
                    ((char*)hbuf + (size_t)(t + 1) * 65536 + (size_t)g * 32768 + s * 256 + r * 16 + w * 8);
                __hip_atomic_store(dst, pk.uv, __ATOMIC_RELAXED, __HIP_MEMORY_SCOPE_AGENT);
            }
            // pacing signal (fire-and-forget; no store ack needed — sentinel backstop)
            if (l == 0) {
                __hip_atomic_fetch_add(mycnt, 1u, __ATOMIC_RELAXED, __HIP_MEMORY_SCOPE_AGENT);
            }
            // ---- off-critical-path work overlapping the counter flight ----
            out[((size_t)(gb0 + r) * 512 + t) * 1024 + u] = h;
            {   // prefetch x_{t+1} into wave-private X[(t+1)&1]
                __bf16* Xn = Xw + ((t + 1) & 1) * 8192;
#pragma unroll
                for (int m = 0; m < 16; ++m) {
                    gload16(xrow + (size_t)(t + 1) * 512 + m * 32 + q * 8, Xn + m * 512);
                }
            }
            // ---- wave-uniform pacing poll (all lanes, uniform addresses) ----
            {
                const unsigned target = 256u * (unsigned)(t + 1) - 16u;   // SLACK=16
                for (;;) {
                    unsigned sum = 0;
#pragma unroll
                    for (int i = 0; i < 64; ++i)
                        sum += __hip_atomic_load(cbase + i * 32, __ATOMIC_RELAXED,
                                                 __HIP_MEMORY_SCOPE_AGENT);
                    if (sum >= target) break;
                }
                // consuming the poll results drained vmcnt -> x DMA complete
            }
            // ---- issue h_{t+1} plain loads; flight overlaps next x-phase ----
            {
                const char* hn = xch + (size_t)(t + 1) * 65536 + (size_t)g * 32768;
#pragma unroll
                for (int j = 0; j < 32; ++j)
                    hv[j] = *(const ulonglong2*)(hn + (j * 4 + q) * 256 + r * 16);
            }
        } else {
            out[((size_t)(gb0 + r) * 512 + t) * 1024 + u] = h;
        }
    }
}

extern "C" void kernel_launch(void* const* d_in, const int* in_sizes, int n_in,
                              void* d_out, int out_size, void* d_ws, size_t ws_size,
                              hipStream_t stream) {
    const float* data = (const float*)d_in[0];
    const float* Wx   = (const float*)d_in[1];
    const float* Wh   = (const float*)d_in[2];
    const float* b    = (const float*)d_in[3];
    float* out = (float*)d_out;

    if (ws_size < (size_t)WS_NEEDED) return;

    char* ws = (char*)d_ws;
    __bf16*   wfrag = (__bf16*)(ws + WS_WFRAG);
    __bf16*   xbuf  = (__bf16*)(ws + WS_XB);
    __bf16*   xchg  = (__bf16*)(ws + WS_XCHG);
    unsigned* cnt   = (unsigned*)(ws + WS_CNT);

    hipFuncSetAttribute((const void*)lstm_main,
                        hipFuncAttributeMaxDynamicSharedMemorySize, LDS_BYTES);

    prep_w_kernel<<<3072, 256, 0, stream>>>(Wx, Wh, wfrag);
    prep_x_kernel<<<8192, 256, 0, stream>>>(data, xbuf);
    hipMemsetAsync(ws + WS_XCHG, 0x00, 65536, stream);                    // slot 0: h_0 = 0
    hipMemsetAsync(ws + WS_XCHG + 65536, 0xFF, 33554432 - 65536, stream); // slots 1..511: sentinel
    hipMemsetAsync(ws + WS_CNT,  0x00, 16384, stream);                    // counters = 0

    lstm_main<<<256, 128, LDS_BYTES, stream>>>(xbuf, wfrag, b, out, xchg, cnt);
}

// Round 5
// 1844.376 us; speedup vs baseline: 6.7585x; 6.7585x over previous
//
#include <hip/hip_runtime.h>
#include <cstdint>
#include <cstddef>

typedef __bf16 bf16x8 __attribute__((ext_vector_type(8)));
typedef __bf16 bf16x4 __attribute__((ext_vector_type(4)));
typedef float  f32x4  __attribute__((ext_vector_type(4)));

// ---------------- ws layout (bytes) ----------------
#define WS_WFRAG   0            // 12,582,912 : fused W bf16 fragments
#define WS_XB      12582912     // 16,777,216 : x in bf16
#define WS_XCHG    29360128     // 33,554,432 : 512 slots * 64 KiB (fresh h exchange)
#define WS_CNT     62914560     // 16,384 : per group 16 counter lines; flags at +8192
#define WS_NEEDED  62930944

// LDS layout (bytes): X0 @0 (16384) | X1 @16384 (16384) | H @32768 (32768) | W @65536 (98304)
#define LDS_BYTES  163840

__device__ __forceinline__ void gload16(const void* g, void* l) {
    __builtin_amdgcn_global_load_lds(
        (const __attribute__((address_space(1))) void*)(g),
        (__attribute__((address_space(3))) void*)(l),
        16, 0, 0);
}

__device__ __forceinline__ float sigmoidf_(float x) {
    return 1.f / (1.f + __expf(-x));
}
__device__ __forceinline__ float tanhf_(float x) {
    x = fminf(fmaxf(x, -15.f), 15.f);
    float e2 = __expf(2.f * x);
    return (e2 - 1.f) / (e2 + 1.f);
}

// ---- prep: shuffle fused W = [Wx ; Wh] into bf16 B-fragment order ----
__global__ void __launch_bounds__(256) prep_w_kernel(const float* __restrict__ Wx,
                                                     const float* __restrict__ Wh,
                                                     __bf16* __restrict__ wfrag) {
    int tid = blockIdx.x * 256 + threadIdx.x;   // 0 .. 786431
    int l   = tid & 63;
    int m   = tid >> 6;
    int nt  = m & 1;
    int sk  = m >> 1;
    int kk  = sk % 48;
    int s   = sk / 48;
    int lc  = l & 15;
    int c   = nt * 16 + lc;
    int uu  = c >> 2;
    int gi  = c & 3;
    int n   = gi * 1024 + s * 8 + uu;
    int k0  = kk * 32 + (l >> 4) * 8;
    bf16x8 v;
#pragma unroll
    for (int j = 0; j < 8; ++j) {
        int k  = k0 + j;
        float f = (k < 512) ? Wx[k * 4096 + n] : Wh[(k - 512) * 4096 + n];
        v[j] = (__bf16)f;
    }
    ((bf16x8*)wfrag)[tid] = v;
}

// ---- prep: cast data fp32 -> bf16 ----
__global__ void __launch_bounds__(256) prep_x_kernel(const float* __restrict__ data,
                                                     __bf16* __restrict__ xb) {
    int tid = blockIdx.x * 256 + threadIdx.x;
    float4 v = ((const float4*)data)[tid];
    bf16x4 o;
    o[0] = (__bf16)v.x; o[1] = (__bf16)v.y; o[2] = (__bf16)v.z; o[3] = (__bf16)v.w;
    ((bf16x4*)xb)[tid] = o;
}

// ---- persistent LSTM kernel ----
// grid = 256 blocks x 128 threads. block -> (g = bid>>7, s = bid&127).
// R1's proven acked-counter protocol with a TREE release:
//  * producers: pack h in LDS -> wave0 stores 2 lines (agent scope) ->
//    s_waitcnt vmcnt(0) -> ONE counter add per block (16-line spread).
//  * fan-in : ONLY block s==0 of each group polls the 16 counter lines
//    (removes the 128-poller vs 8-add L3 line contention of R1).
//  * fan-out: master publishes flag = t+1 (own line); 127 blocks poll the
//    single read-only flag word.
//  * consumers then plain-cached-load h (fresh address per step -> no
//    staleness; flag implies h stores acked at L3).
__global__ void __launch_bounds__(128)
lstm_main(const __bf16* __restrict__ xb, const __bf16* __restrict__ wfrag,
          const float* __restrict__ bias, float* __restrict__ out,
          __bf16* __restrict__ hbuf, unsigned* __restrict__ cnt) {
    extern __shared__ char smem[];
    __bf16* X_lds = (__bf16*)smem;                 // 2 buffers * 16 chunks * 512 bf16
    __bf16* H_lds = (__bf16*)(smem + 32768);       // 32 chunks * 512 bf16
    __bf16* W_lds = (__bf16*)(smem + 65536);       // 96 chunks * 512 bf16

    const int tid = threadIdx.x;
    const int l   = tid & 63;
    const int w   = tid >> 6;        // wave id == N-tile id (0,1)
    const int q   = l >> 4;
    const int r   = l & 15;
    const int bid = blockIdx.x;
    const int s   = bid & 127;
    const int g   = bid >> 7;
    const int gb0 = g * 16;

    // ---- stage W slice into LDS (once) ----
    const __bf16* wsrc = wfrag + (size_t)s * 49152;
    for (int m = w * 48; m < w * 48 + 48; ++m) {
        gload16(wsrc + m * 512 + l * 8, W_lds + m * 512);
    }

    const int uu = w * 4 + q;
    const int u  = s * 8 + uu;
    const float b_i = bias[u];
    const float b_f = bias[1024 + u];
    const float b_g = bias[2048 + u];
    const float b_o = bias[3072 + u];
    float cst = 0.f;

    unsigned* cbase = cnt + g * 1024;              // 16 lines * 64 uints (256B spacing)
    unsigned* mycnt = cbase + (s & 15) * 64;
    unsigned* flag  = cnt + 2048 + g * 64;         // own line per group

    // ---- prefetch x_0 into X buffer 0 ----
    {
        const __bf16* xrow = xb + (size_t)(gb0 + r) * 512 * 512;
#pragma unroll
        for (int j = 0; j < 8; ++j) {
            int m = w * 8 + j;
            gload16(xrow + m * 32 + q * 8, X_lds + m * 512);
        }
    }

    __syncthreads();   // W + x_0 staged (drains vmcnt)

    for (int t = 0; t < 512; ++t) {
        // ---- load h_t straight into registers (plain cached; fresh address) ----
        unsigned long long va[16], vb[16];
        {
            const __bf16* hsrc = hbuf + (size_t)t * 32768 + (size_t)g * 16384;
#pragma unroll
            for (int j = 0; j < 16; ++j) {
                int m = w * 16 + j;
                ulonglong2 v = *(const ulonglong2*)(hsrc + (m * 4 + q) * 128 + r * 8);
                va[j] = v.x; vb[j] = v.y;
            }
        }

        // ---- x-part MFMAs overlap the h-load flight ----
        const __bf16* Xc = X_lds + (t & 1) * 8192;
        f32x4 acc0 = {0.f, 0.f, 0.f, 0.f};
        f32x4 acc1 = {0.f, 0.f, 0.f, 0.f};
#pragma unroll
        for (int kk = 0; kk < 16; kk += 2) {
            bf16x8 a0 = *(const bf16x8*)(Xc + kk * 512 + l * 8);
            bf16x8 b0 = *(const bf16x8*)(W_lds + (kk * 2 + w) * 512 + l * 8);
            acc0 = __builtin_amdgcn_mfma_f32_16x16x32_bf16(a0, b0, acc0, 0, 0, 0);
            bf16x8 a1 = *(const bf16x8*)(Xc + (kk + 1) * 512 + l * 8);
            bf16x8 b1 = *(const bf16x8*)(W_lds + ((kk + 1) * 2 + w) * 512 + l * 8);
            acc1 = __builtin_amdgcn_mfma_f32_16x16x32_bf16(a1, b1, acc1, 0, 0, 0);
        }

        // ---- stage h into LDS (cross-wave share) ----
#pragma unroll
        for (int j = 0; j < 16; ++j) {
            int m = w * 16 + j;
            unsigned long long tmp[2] = {va[j], vb[j]};
            *((ulonglong2*)(H_lds + m * 512 + l * 8)) = *(const ulonglong2*)tmp;
        }
        __syncthreads();   // h staged

        // ---- h-part MFMAs: 32 chained, 2 accumulators (order preserved) ----
#pragma unroll 4
        for (int kk = 16; kk < 48; kk += 2) {
            bf16x8 a0 = *(const bf16x8*)(H_lds + (kk - 16) * 512 + l * 8);
            bf16x8 b0 = *(const bf16x8*)(W_lds + (kk * 2 + w) * 512 + l * 8);
            acc0 = __builtin_amdgcn_mfma_f32_16x16x32_bf16(a0, b0, acc0, 0, 0, 0);
            bf16x8 a1 = *(const bf16x8*)(H_lds + (kk - 15) * 512 + l * 8);
            bf16x8 b1 = *(const bf16x8*)(W_lds + ((kk + 1) * 2 + w) * 512 + l * 8);
            acc1 = __builtin_amdgcn_mfma_f32_16x16x32_bf16(a1, b1, acc1, 0, 0, 0);
        }

        // ---- regroup gates via scratch overlaid on the DEAD x buffer ----
        float*  scr   = (float*)(smem + ((t + 1) & 1) * 16384);
        __bf16* hpack = (__bf16*)(smem + ((t + 1) & 1) * 16384 + 2176);
        float* sw = scr + w * 272;
#pragma unroll
        for (int rg = 0; rg < 4; ++rg) {
            sw[(l & 15) * 17 + q * 4 + rg] = acc0[rg] + acc1[rg];
        }
        float xi = sw[(q * 4 + 0) * 17 + r];
        float xf = sw[(q * 4 + 1) * 17 + r];
        float xg = sw[(q * 4 + 2) * 17 + r];
        float xo = sw[(q * 4 + 3) * 17 + r];

        float ii = sigmoidf_(xi + b_i);
        float ff = sigmoidf_(xf + b_f);
        float gg = tanhf_(xg + b_g);
        float oo = sigmoidf_(xo + b_o);
        cst = ff * cst + ii * gg;
        float h = oo * tanhf_(cst);

        const int bglob = gb0 + r;

        if (t < 511) {
            hpack[r * 8 + uu] = (__bf16)h;
            __syncthreads();   // hpack ready (both waves done with MFMA/scratch)
            if (w == 0) {
                if (tid < 32) {
                    unsigned long long v = ((const unsigned long long*)hpack)[tid];
                    // block-major: 256 B contiguous per (t+1, g, s) = 2 whole lines
                    unsigned long long* dst = (unsigned long long*)
                        (hbuf + (size_t)(t + 1) * 32768 + (size_t)g * 16384 + s * 128) + tid;
                    __hip_atomic_store(dst, v, __ATOMIC_RELAXED, __HIP_MEMORY_SCOPE_AGENT);
                }
                __asm__ __volatile__("s_waitcnt vmcnt(0)" ::: "memory");
                if (tid == 0) {
                    __hip_atomic_fetch_add(mycnt, 1u, __ATOMIC_RELAXED, __HIP_MEMORY_SCOPE_AGENT);
                }
            }
            // ---- off-critical-path work overlapping the release ----
            out[((size_t)bglob * 512 + t) * 1024 + u] = h;
            {   // prefetch x_{t+1} into X[(t+1)&1] (clobbers scr/hpack — both dead)
                const __bf16* xrow = xb + ((size_t)(gb0 + r) * 512 + (t + 1)) * 512;
                __bf16* Xn = X_lds + ((t + 1) & 1) * 8192;
#pragma unroll
                for (int j = 0; j < 8; ++j) {
                    int m = w * 8 + j;
                    gload16(xrow + m * 32 + q * 8, Xn + m * 512);
                }
            }
            if (tid == 0) {
                if (s == 0) {
                    // ---- fan-in: sole poller of the counter lines ----
                    const unsigned target = 128u * (unsigned)(t + 1);
                    for (;;) {
                        unsigned sum = 0;
#pragma unroll
                        for (int i = 0; i < 16; ++i)
                            sum += __hip_atomic_load(cbase + i * 64, __ATOMIC_RELAXED,
                                                     __HIP_MEMORY_SCOPE_AGENT);
                        if (sum >= target) break;
                    }
                    // ---- fan-out: publish release ----
                    __hip_atomic_store(flag, (unsigned)(t + 1), __ATOMIC_RELAXED,
                                       __HIP_MEMORY_SCOPE_AGENT);
                } else {
                    // ---- poll the single read-only flag word ----
                    while (__hip_atomic_load(flag, __ATOMIC_RELAXED,
                                             __HIP_MEMORY_SCOPE_AGENT) < (unsigned)(t + 1)) {}
                }
            }
            __syncthreads();   // release; drains out store + x prefetch
        } else {
            out[((size_t)bglob * 512 + t) * 1024 + u] = h;
        }
    }
}

extern "C" void kernel_launch(void* const* d_in, const int* in_sizes, int n_in,
                              void* d_out, int out_size, void* d_ws, size_t ws_size,
                              hipStream_t stream) {
    const float* data = (const float*)d_in[0];
    const float* Wx   = (const float*)d_in[1];
    const float* Wh   = (const float*)d_in[2];
    const float* b    = (const float*)d_in[3];
    float* out = (float*)d_out;

    if (ws_size < (size_t)WS_NEEDED) return;

    char* ws = (char*)d_ws;
    __bf16*   wfrag = (__bf16*)(ws + WS_WFRAG);
    __bf16*   xbuf  = (__bf16*)(ws + WS_XB);
    __bf16*   xchg  = (__bf16*)(ws + WS_XCHG);
    unsigned* cnt   = (unsigned*)(ws + WS_CNT);

    hipFuncSetAttribute((const void*)lstm_main,
                        hipFuncAttributeMaxDynamicSharedMemorySize, LDS_BYTES);

    prep_w_kernel<<<3072, 256, 0, stream>>>(Wx, Wh, wfrag);
    prep_x_kernel<<<8192, 256, 0, stream>>>(data, xbuf);
    hipMemsetAsync(ws + WS_XCHG, 0x00, 65536, stream);   // slot 0: h_0 = 0
    hipMemsetAsync(ws + WS_CNT,  0x00, 16384, stream);   // counters + flags = 0

    lstm_main<<<256, 128, LDS_BYTES, stream>>>(xbuf, wfrag, b, out, xchg, cnt);
}